// Round 1
// baseline (2232.712 us; speedup 1.0000x reference)
//
#include <hip/hip_runtime.h>

#define HW 16384   // 128*128
#define CDIM 192

// ---------------------------------------------------------------------------
// 1x1 conv as GEMM: Out[b,m,p] = sum_k Wm[m,k] * Bmat[b,k,p] + bias[m]
// M=192 (2 tiles of 128 with guard), K=192, N=16384.
// 128x128 block tile, BK=16, 8x8 per thread (split quadrants r0/r0+64, c0/c0+64).
// ---------------------------------------------------------------------------
__global__ __launch_bounds__(256) void k_conv1x1(
    const float* __restrict__ Bmat, const float* __restrict__ Wm,
    const float* __restrict__ bias, float* __restrict__ Out)
{
  const int t  = threadIdx.x;
  const int b  = blockIdx.z;
  const int m0 = blockIdx.y * 128;
  const int n0 = blockIdx.x * 128;
  const float* Bp = Bmat + (size_t)b * CDIM * HW;
  float* Op = Out + (size_t)b * CDIM * HW;

  __shared__ float As[16][132];   // [k][m], pad 132 breaks store conflicts
  __shared__ float Bs[16][132];   // [k][n]

  const int ar = t >> 2, ac = (t & 3) << 2;      // A: 64 rows/pass, 16 cols
  const int br = t >> 5, bc = (t & 31) << 2;     // B: 8 rows/pass, 128 cols
  const int r0 = (t >> 4) << 2, c0 = (t & 15) << 2;

  float acc[8][8] = {};

  for (int k0 = 0; k0 < CDIM; k0 += 16) {
    float4 a0 = make_float4(0.f, 0.f, 0.f, 0.f), a1 = a0;
    if (m0 + ar < CDIM)      a0 = *(const float4*)&Wm[(m0 + ar) * CDIM + k0 + ac];
    if (m0 + ar + 64 < CDIM) a1 = *(const float4*)&Wm[(m0 + ar + 64) * CDIM + k0 + ac];
    float4 b0 = *(const float4*)&Bp[(size_t)(k0 + br) * HW + n0 + bc];
    float4 b1 = *(const float4*)&Bp[(size_t)(k0 + br + 8) * HW + n0 + bc];

    __syncthreads();
    As[ac + 0][ar] = a0.x; As[ac + 1][ar] = a0.y; As[ac + 2][ar] = a0.z; As[ac + 3][ar] = a0.w;
    As[ac + 0][ar + 64] = a1.x; As[ac + 1][ar + 64] = a1.y; As[ac + 2][ar + 64] = a1.z; As[ac + 3][ar + 64] = a1.w;
    *(float4*)&Bs[br][bc]     = b0;
    *(float4*)&Bs[br + 8][bc] = b1;
    __syncthreads();

    #pragma unroll
    for (int kk = 0; kk < 16; ++kk) {
      float a_[8], b_[8];
      *(float4*)&a_[0] = *(const float4*)&As[kk][r0];
      *(float4*)&a_[4] = *(const float4*)&As[kk][r0 + 64];
      *(float4*)&b_[0] = *(const float4*)&Bs[kk][c0];
      *(float4*)&b_[4] = *(const float4*)&Bs[kk][c0 + 64];
      #pragma unroll
      for (int i = 0; i < 8; ++i)
        #pragma unroll
        for (int j = 0; j < 8; ++j)
          acc[i][j] = fmaf(a_[i], b_[j], acc[i][j]);
    }
  }

  #pragma unroll
  for (int i = 0; i < 8; ++i) {
    const int m = m0 + r0 + (i < 4 ? i : 60 + i);
    if (m >= CDIM) continue;
    const float bv = bias[m];
    float4 o0 = make_float4(acc[i][0] + bv, acc[i][1] + bv, acc[i][2] + bv, acc[i][3] + bv);
    float4 o1 = make_float4(acc[i][4] + bv, acc[i][5] + bv, acc[i][6] + bv, acc[i][7] + bv);
    *(float4*)&Op[(size_t)m * HW + n0 + c0]      = o0;
    *(float4*)&Op[(size_t)m * HW + n0 + c0 + 64] = o1;
  }
}

// ---------------------------------------------------------------------------
// Depthwise 3x3 + bias + to_heads permutation + (optional) l2 norm.
// One block per output row (b, head, dh); row length n = 1024.
// src: (8,192,128,128) conv1 output for this qkv slice.
// dst: (8,4,768,1024).  dh = c*16 + fx*4 + fy ; n = h1*32 + w1 ;
// pixel = (h1*4+fy, w1*4+fx); channel-in-slice = head*48 + c.
// ---------------------------------------------------------------------------
__global__ __launch_bounds__(256) void k_dw_norm(
    const float* __restrict__ src,
    const float* __restrict__ dww, const float* __restrict__ dwb,
    float* __restrict__ dst, int sel)
{
  int id = blockIdx.x;
  const int dh = id % 768; id /= 768;
  const int head = id & 3;
  const int b = id >> 2;
  const int c = dh >> 4, rr = dh & 15, fx = rr >> 2, fy = rr & 3;
  const int chl = head * 48 + c;        // channel within this 192-slice
  const int ch  = sel * 192 + chl;      // global channel (for dw weights/bias)
  const float* img = src + ((size_t)b * CDIM + chl) * HW;

  float wgt[9];
  #pragma unroll
  for (int i = 0; i < 9; ++i) wgt[i] = dww[ch * 9 + i];
  const float bias = dwb[ch];

  const int t = threadIdx.x;
  float vals[4];
  float sq = 0.f;
  #pragma unroll
  for (int j = 0; j < 4; ++j) {
    const int n = t + j * 256;
    const int h = ((n >> 5) << 2) + fy;
    const int w = ((n & 31) << 2) + fx;
    float acc = bias;
    #pragma unroll
    for (int dy = -1; dy <= 1; ++dy) {
      const int hh = h + dy;
      if (hh < 0 || hh > 127) continue;
      #pragma unroll
      for (int dx = -1; dx <= 1; ++dx) {
        const int ww = w + dx;
        if (ww < 0 || ww > 127) continue;
        acc = fmaf(img[hh * 128 + ww], wgt[(dy + 1) * 3 + (dx + 1)], acc);
      }
    }
    vals[j] = acc;
    sq = fmaf(acc, acc, sq);
  }

  float* row = dst + ((size_t)(b * 4 + head) * 768 + dh) * 1024;

  if (sel == 2) {   // v: no normalization
    #pragma unroll
    for (int j = 0; j < 4; ++j) row[t + j * 256] = vals[j];
    return;
  }

  __shared__ float red[256];
  red[t] = sq;
  __syncthreads();
  for (int s = 128; s > 0; s >>= 1) {
    if (t < s) red[t] += red[t + s];
    __syncthreads();
  }
  const float denom = fmaxf(sqrtf(red[0]), 1e-12f);
  #pragma unroll
  for (int j = 0; j < 4; ++j) row[t + j * 256] = vals[j] / denom;
}

// ---------------------------------------------------------------------------
// S = Q * K^T per (b,head).  M=N=768, Kdim=1024. Both tiles transposed-stored.
// ---------------------------------------------------------------------------
__global__ __launch_bounds__(256) void k_qk(
    const float* __restrict__ Q, const float* __restrict__ Kt,
    float* __restrict__ S)
{
  const int t  = threadIdx.x;
  const int bh = blockIdx.z;
  const int m0 = blockIdx.y * 128;
  const int n0 = blockIdx.x * 128;
  const float* Qp = Q  + (size_t)bh * 768 * 1024;
  const float* Kp = Kt + (size_t)bh * 768 * 1024;
  float* Sp = S + (size_t)bh * 768 * 768;

  __shared__ float As[16][132];
  __shared__ float Bs[16][132];

  const int ar = t >> 2, ac = (t & 3) << 2;
  const int r0 = (t >> 4) << 2, c0 = (t & 15) << 2;

  float acc[8][8] = {};

  for (int k0 = 0; k0 < 1024; k0 += 16) {
    float4 a0 = *(const float4*)&Qp[(size_t)(m0 + ar) * 1024 + k0 + ac];
    float4 a1 = *(const float4*)&Qp[(size_t)(m0 + ar + 64) * 1024 + k0 + ac];
    float4 b0 = *(const float4*)&Kp[(size_t)(n0 + ar) * 1024 + k0 + ac];
    float4 b1 = *(const float4*)&Kp[(size_t)(n0 + ar + 64) * 1024 + k0 + ac];

    __syncthreads();
    As[ac + 0][ar] = a0.x; As[ac + 1][ar] = a0.y; As[ac + 2][ar] = a0.z; As[ac + 3][ar] = a0.w;
    As[ac + 0][ar + 64] = a1.x; As[ac + 1][ar + 64] = a1.y; As[ac + 2][ar + 64] = a1.z; As[ac + 3][ar + 64] = a1.w;
    Bs[ac + 0][ar] = b0.x; Bs[ac + 1][ar] = b0.y; Bs[ac + 2][ar] = b0.z; Bs[ac + 3][ar] = b0.w;
    Bs[ac + 0][ar + 64] = b1.x; Bs[ac + 1][ar + 64] = b1.y; Bs[ac + 2][ar + 64] = b1.z; Bs[ac + 3][ar + 64] = b1.w;
    __syncthreads();

    #pragma unroll
    for (int kk = 0; kk < 16; ++kk) {
      float a_[8], b_[8];
      *(float4*)&a_[0] = *(const float4*)&As[kk][r0];
      *(float4*)&a_[4] = *(const float4*)&As[kk][r0 + 64];
      *(float4*)&b_[0] = *(const float4*)&Bs[kk][c0];
      *(float4*)&b_[4] = *(const float4*)&Bs[kk][c0 + 64];
      #pragma unroll
      for (int i = 0; i < 8; ++i)
        #pragma unroll
        for (int j = 0; j < 8; ++j)
          acc[i][j] = fmaf(a_[i], b_[j], acc[i][j]);
    }
  }

  #pragma unroll
  for (int i = 0; i < 8; ++i) {
    const int m = m0 + r0 + (i < 4 ? i : 60 + i);
    float4 o0 = make_float4(acc[i][0], acc[i][1], acc[i][2], acc[i][3]);
    float4 o1 = make_float4(acc[i][4], acc[i][5], acc[i][6], acc[i][7]);
    *(float4*)&Sp[(size_t)m * 768 + n0 + c0]      = o0;
    *(float4*)&Sp[(size_t)m * 768 + n0 + c0 + 64] = o1;
  }
}

// ---------------------------------------------------------------------------
// softmax_1 over rows of 768: e = exp(s*temp[head]); s = e/(sum(e)+1)
// ---------------------------------------------------------------------------
__global__ __launch_bounds__(256) void k_softmax1(
    float* __restrict__ S, const float* __restrict__ temp)
{
  const int row = blockIdx.x;               // ((b*4+head)*768 + d)
  const float tp = temp[(row / 768) & 3];
  float* r = S + (size_t)row * 768;
  const int t = threadIdx.x;

  float e[3];
  float s = 0.f;
  #pragma unroll
  for (int j = 0; j < 3; ++j) {
    e[j] = expf(r[t + j * 256] * tp);
    s += e[j];
  }
  __shared__ float red[256];
  red[t] = s;
  __syncthreads();
  for (int st = 128; st > 0; st >>= 1) {
    if (t < st) red[t] += red[t + st];
    __syncthreads();
  }
  const float denom = red[0] + 1.0f;
  #pragma unroll
  for (int j = 0; j < 3; ++j) r[t + j * 256] = e[j] / denom;
}

// ---------------------------------------------------------------------------
// O = S * V per (b,head); epilogue does from_heads scatter directly:
// P[b, head*48 + d/16, (n/32)*4 + d%4, (n%32)*4 + (d/4)%4] = O[d,n]
// M=768, N=1024, Kdim=768.
// ---------------------------------------------------------------------------
__global__ __launch_bounds__(256) void k_av(
    const float* __restrict__ S, const float* __restrict__ V,
    float* __restrict__ P)
{
  const int t  = threadIdx.x;
  const int bh = blockIdx.z;
  const int head = bh & 3, b = bh >> 2;
  const int m0 = blockIdx.y * 128;
  const int n0 = blockIdx.x * 128;
  const float* Sp = S + (size_t)bh * 768 * 768;
  const float* Vp = V + (size_t)bh * 768 * 1024;

  __shared__ float As[16][132];
  __shared__ float Bs[16][132];

  const int ar = t >> 2, ac = (t & 3) << 2;
  const int br = t >> 5, bc = (t & 31) << 2;
  const int r0 = (t >> 4) << 2, c0 = (t & 15) << 2;

  float acc[8][8] = {};

  for (int k0 = 0; k0 < 768; k0 += 16) {
    float4 a0 = *(const float4*)&Sp[(size_t)(m0 + ar) * 768 + k0 + ac];
    float4 a1 = *(const float4*)&Sp[(size_t)(m0 + ar + 64) * 768 + k0 + ac];
    float4 b0 = *(const float4*)&Vp[(size_t)(k0 + br) * 1024 + n0 + bc];
    float4 b1 = *(const float4*)&Vp[(size_t)(k0 + br + 8) * 1024 + n0 + bc];

    __syncthreads();
    As[ac + 0][ar] = a0.x; As[ac + 1][ar] = a0.y; As[ac + 2][ar] = a0.z; As[ac + 3][ar] = a0.w;
    As[ac + 0][ar + 64] = a1.x; As[ac + 1][ar + 64] = a1.y; As[ac + 2][ar + 64] = a1.z; As[ac + 3][ar + 64] = a1.w;
    *(float4*)&Bs[br][bc]     = b0;
    *(float4*)&Bs[br + 8][bc] = b1;
    __syncthreads();

    #pragma unroll
    for (int kk = 0; kk < 16; ++kk) {
      float a_[8], b_[8];
      *(float4*)&a_[0] = *(const float4*)&As[kk][r0];
      *(float4*)&a_[4] = *(const float4*)&As[kk][r0 + 64];
      *(float4*)&b_[0] = *(const float4*)&Bs[kk][c0];
      *(float4*)&b_[4] = *(const float4*)&Bs[kk][c0 + 64];
      #pragma unroll
      for (int i = 0; i < 8; ++i)
        #pragma unroll
        for (int j = 0; j < 8; ++j)
          acc[i][j] = fmaf(a_[i], b_[j], acc[i][j]);
    }
  }

  float* Pb = P + (size_t)b * CDIM * HW;
  #pragma unroll
  for (int i = 0; i < 8; ++i) {
    const int d = m0 + r0 + (i < 4 ? i : 60 + i);
    const int ch = head * 48 + (d >> 4);
    const int fx = (d >> 2) & 3, fy = d & 3;
    float* Pc = Pb + (size_t)ch * HW;
    #pragma unroll
    for (int j = 0; j < 8; ++j) {
      const int n = n0 + c0 + (j < 4 ? j : 60 + j);
      const int h = ((n >> 5) << 2) + fy;
      const int w = ((n & 31) << 2) + fx;
      Pc[h * 128 + w] = acc[i][j];
    }
  }
}

// ---------------------------------------------------------------------------
extern "C" void kernel_launch(void* const* d_in, const int* in_sizes, int n_in,
                              void* d_out, int out_size, void* d_ws, size_t ws_size,
                              hipStream_t stream) {
  const float* x      = (const float*)d_in[0];
  const float* qkv_w  = (const float*)d_in[1];
  const float* qkv_b  = (const float*)d_in[2];
  const float* dw_w   = (const float*)d_in[3];
  const float* dw_b   = (const float*)d_in[4];
  const float* proj_w = (const float*)d_in[5];
  const float* proj_b = (const float*)d_in[6];
  const float* temp   = (const float*)d_in[7];
  float* out = (float*)d_out;

  float* ws = (float*)d_ws;
  const size_t SZ = (size_t)8 * CDIM * HW;   // 25,165,824 floats
  float* tmp = ws;            // conv1 slice output; later aliased by S
  float* Qb  = ws + SZ;       // later aliased by P
  float* Kb  = ws + 2 * SZ;
  float* Vb  = ws + 3 * SZ;
  float* Sb  = tmp;           // 8*4*768*768 = 18,874,368 floats < SZ
  float* Pb  = Qb;            // Q dead after k_qk

  for (int sel = 0; sel < 3; ++sel) {
    k_conv1x1<<<dim3(128, 2, 8), 256, 0, stream>>>(
        x, qkv_w + sel * CDIM * CDIM, qkv_b + sel * CDIM, tmp);
    float* dst = (sel == 0) ? Qb : ((sel == 1) ? Kb : Vb);
    k_dw_norm<<<dim3(8 * 4 * 768), 256, 0, stream>>>(tmp, dw_w, dw_b, dst, sel);
  }

  k_qk<<<dim3(6, 6, 32), 256, 0, stream>>>(Qb, Kb, Sb);
  k_softmax1<<<dim3(8 * 4 * 768), 256, 0, stream>>>(Sb, temp);
  k_av<<<dim3(8, 6, 32), 256, 0, stream>>>(Sb, Vb, Pb);
  k_conv1x1<<<dim3(128, 2, 8), 256, 0, stream>>>(Pb, proj_w, proj_b, out);
}

// Round 2
// 1672.391 us; speedup vs baseline: 1.3350x; 1.3350x over previous
//
#include <hip/hip_runtime.h>

#define HW 16384   // 128*128
#define CDIM 192

typedef short bf16x8 __attribute__((ext_vector_type(8)));
typedef float f32x4  __attribute__((ext_vector_type(4)));

__device__ inline void gload_lds16(const void* g, void* l) {
  __builtin_amdgcn_global_load_lds(
      (const __attribute__((address_space(1))) void*)g,
      (__attribute__((address_space(3))) void*)l, 16, 0, 0);
}

__device__ inline short to_bf16_rne(float f) {
  unsigned u = __float_as_uint(f);
  unsigned r = u + 0x7fffu + ((u >> 16) & 1u);
  return (short)(r >> 16);
}

__device__ inline void split_bf16(float a, short& hi, short& lo) {
  unsigned u = __float_as_uint(a);
  hi = (short)(u >> 16);                       // truncated high part
  float res = a - __uint_as_float(u & 0xffff0000u);
  lo = (short)(__float_as_uint(res) >> 16);    // residual, ~2^-17 accurate total
}

// ---------------------------------------------------------------------------
// 1x1 conv as GEMM (fp32 VALU this round): Out[b,m,p] = W[m,k]*B[b,k,p]+bias
// ---------------------------------------------------------------------------
__global__ __launch_bounds__(256) void k_conv1x1(
    const float* __restrict__ Bmat, const float* __restrict__ Wm,
    const float* __restrict__ bias, float* __restrict__ Out)
{
  const int t  = threadIdx.x;
  const int b  = blockIdx.z;
  const int m0 = blockIdx.y * 128;
  const int n0 = blockIdx.x * 128;
  const float* Bp = Bmat + (size_t)b * CDIM * HW;
  float* Op = Out + (size_t)b * CDIM * HW;

  __shared__ float As[16][132];
  __shared__ float Bs[16][132];

  const int ar = t >> 2, ac = (t & 3) << 2;
  const int br = t >> 5, bc = (t & 31) << 2;
  const int r0 = (t >> 4) << 2, c0 = (t & 15) << 2;

  float acc[8][8] = {};

  for (int k0 = 0; k0 < CDIM; k0 += 16) {
    float4 a0 = make_float4(0.f, 0.f, 0.f, 0.f), a1 = a0;
    if (m0 + ar < CDIM)      a0 = *(const float4*)&Wm[(m0 + ar) * CDIM + k0 + ac];
    if (m0 + ar + 64 < CDIM) a1 = *(const float4*)&Wm[(m0 + ar + 64) * CDIM + k0 + ac];
    float4 b0 = *(const float4*)&Bp[(size_t)(k0 + br) * HW + n0 + bc];
    float4 b1 = *(const float4*)&Bp[(size_t)(k0 + br + 8) * HW + n0 + bc];

    __syncthreads();
    As[ac + 0][ar] = a0.x; As[ac + 1][ar] = a0.y; As[ac + 2][ar] = a0.z; As[ac + 3][ar] = a0.w;
    As[ac + 0][ar + 64] = a1.x; As[ac + 1][ar + 64] = a1.y; As[ac + 2][ar + 64] = a1.z; As[ac + 3][ar + 64] = a1.w;
    *(float4*)&Bs[br][bc]     = b0;
    *(float4*)&Bs[br + 8][bc] = b1;
    __syncthreads();

    #pragma unroll
    for (int kk = 0; kk < 16; ++kk) {
      float a_[8], b_[8];
      *(float4*)&a_[0] = *(const float4*)&As[kk][r0];
      *(float4*)&a_[4] = *(const float4*)&As[kk][r0 + 64];
      *(float4*)&b_[0] = *(const float4*)&Bs[kk][c0];
      *(float4*)&b_[4] = *(const float4*)&Bs[kk][c0 + 64];
      #pragma unroll
      for (int i = 0; i < 8; ++i)
        #pragma unroll
        for (int j = 0; j < 8; ++j)
          acc[i][j] = fmaf(a_[i], b_[j], acc[i][j]);
    }
  }

  #pragma unroll
  for (int i = 0; i < 8; ++i) {
    const int m = m0 + r0 + (i < 4 ? i : 60 + i);
    if (m >= CDIM) continue;
    const float bv = bias[m];
    float4 o0 = make_float4(acc[i][0] + bv, acc[i][1] + bv, acc[i][2] + bv, acc[i][3] + bv);
    float4 o1 = make_float4(acc[i][4] + bv, acc[i][5] + bv, acc[i][6] + bv, acc[i][7] + bv);
    *(float4*)&Op[(size_t)m * HW + n0 + c0]      = o0;
    *(float4*)&Op[(size_t)m * HW + n0 + c0 + 64] = o1;
  }
}

// ---------------------------------------------------------------------------
// Depthwise 3x3 + bias + to_heads + l2norm (q,k -> split bf16) / V (fp32)
// dst layout q/k: [bh][768][1024] hi+lo bf16 ; V: fp32 same layout
// ---------------------------------------------------------------------------
__global__ __launch_bounds__(256) void k_dw_norm(
    const float* __restrict__ src,
    const float* __restrict__ dww, const float* __restrict__ dwb,
    short* __restrict__ dsth, short* __restrict__ dstl,
    float* __restrict__ dstv, int sel)
{
  int id = blockIdx.x;
  const int dh = id % 768; id /= 768;
  const int head = id & 3;
  const int b = id >> 2;
  const int c = dh >> 4, rr = dh & 15, fx = rr >> 2, fy = rr & 3;
  const int chl = head * 48 + c;
  const int ch  = sel * 192 + chl;
  const float* img = src + ((size_t)b * CDIM + chl) * HW;

  float wgt[9];
  #pragma unroll
  for (int i = 0; i < 9; ++i) wgt[i] = dww[ch * 9 + i];
  const float bias = dwb[ch];

  const int t = threadIdx.x;
  float vals[4];
  float sq = 0.f;
  #pragma unroll
  for (int j = 0; j < 4; ++j) {
    const int n = t + j * 256;
    const int h = ((n >> 5) << 2) + fy;
    const int w = ((n & 31) << 2) + fx;
    float acc = bias;
    #pragma unroll
    for (int dy = -1; dy <= 1; ++dy) {
      const int hh = h + dy;
      if (hh < 0 || hh > 127) continue;
      #pragma unroll
      for (int dx = -1; dx <= 1; ++dx) {
        const int ww = w + dx;
        if (ww < 0 || ww > 127) continue;
        acc = fmaf(img[hh * 128 + ww], wgt[(dy + 1) * 3 + (dx + 1)], acc);
      }
    }
    vals[j] = acc;
    sq = fmaf(acc, acc, sq);
  }

  const size_t rowoff = ((size_t)(b * 4 + head) * 768 + dh) * 1024;

  if (sel == 2) {   // v: fp32, no normalization
    float* row = dstv + rowoff;
    #pragma unroll
    for (int j = 0; j < 4; ++j) row[t + j * 256] = vals[j];
    return;
  }

  __shared__ float red[256];
  red[t] = sq;
  __syncthreads();
  for (int s = 128; s > 0; s >>= 1) {
    if (t < s) red[t] += red[t + s];
    __syncthreads();
  }
  const float denom = fmaxf(sqrtf(red[0]), 1e-12f);
  short* rh = dsth + rowoff;
  short* rl = dstl + rowoff;
  #pragma unroll
  for (int j = 0; j < 4; ++j) {
    short hi, lo;
    split_bf16(vals[j] / denom, hi, lo);
    rh[t + j * 256] = hi;
    rl[t + j * 256] = lo;
  }
}

// ---------------------------------------------------------------------------
// V fp32 [bh][768(e)][1024(n)] -> Vt bf16 [bh][1024(n)][768(e)]
// ---------------------------------------------------------------------------
__global__ __launch_bounds__(256) void k_vt(
    const float* __restrict__ V, short* __restrict__ Vtb)
{
  __shared__ float ls[64][65];
  const int t = threadIdx.x;
  const int bh = blockIdx.z;
  const int e0 = blockIdx.y * 64, n0 = blockIdx.x * 64;
  const float* Vp = V + (size_t)bh * 768 * 1024;
  short* Tp = Vtb + (size_t)bh * 1024 * 768;

  #pragma unroll
  for (int it = 0; it < 4; ++it) {
    const int e = (t >> 4) + it * 16, n = (t & 15) * 4;
    *(float4*)&ls[e][n] = *(const float4*)&Vp[(size_t)(e0 + e) * 1024 + n0 + n];
  }
  __syncthreads();
  #pragma unroll
  for (int it = 0; it < 4; ++it) {
    const int n = (t >> 4) + it * 16, e = (t & 15) * 4;
    short4 o;
    o.x = to_bf16_rne(ls[e + 0][n]);
    o.y = to_bf16_rne(ls[e + 1][n]);
    o.z = to_bf16_rne(ls[e + 2][n]);
    o.w = to_bf16_rne(ls[e + 3][n]);
    *(short4*)&Tp[(size_t)(n0 + n) * 768 + e0 + e] = o;
  }
}

// ---------------------------------------------------------------------------
// S = Q*K^T via MFMA with hi/lo bf16 split (3-term). M=N=768, K=1024 per bh.
// 128x128 tile, BK=32, 4 waves in 2x2, each 64x64 (4x4 MFMA tiles).
// LDS fragment-order layout filled by global_load_lds width=16.
// ---------------------------------------------------------------------------
__global__ __launch_bounds__(256) void k_qk(
    const short* __restrict__ Qhi, const short* __restrict__ Qlo,
    const short* __restrict__ Khi, const short* __restrict__ Klo,
    float* __restrict__ S)
{
  __shared__ short lds[4][4096];   // A_hi, A_lo, B_hi, B_lo (8 KB each)
  const int t = threadIdx.x, lane = t & 63, w = t >> 6;
  const int lr = lane & 15, lq = lane >> 4;
  const int bh = blockIdx.z, m0 = blockIdx.y * 128, n0 = blockIdx.x * 128;
  const size_t base = (size_t)bh * 768 * 1024;

  const short* src = (w == 0) ? Qhi : (w == 1) ? Qlo : (w == 2) ? Khi : Klo;
  src += base;
  const int row0 = (w < 2) ? m0 : n0;

  f32x4 acc[4][4] = {};
  const int wm = (w >> 1) * 4, wn = (w & 1) * 4;

  for (int k0 = 0; k0 < 1024; k0 += 32) {
    __syncthreads();
    #pragma unroll
    for (int s = 0; s < 8; ++s) {
      const short* g = src + (size_t)(row0 + s * 16 + lr) * 1024 + k0 + lq * 8;
      gload_lds16(g, &lds[w][s * 512]);   // lds dest = uniform base + lane*16B
    }
    __syncthreads();

    bf16x8 ah[4], al[4], bhf[4], blf[4];
    #pragma unroll
    for (int i = 0; i < 4; ++i) {
      ah[i]  = *(const bf16x8*)&lds[0][(wm + i) * 512 + lane * 8];
      al[i]  = *(const bf16x8*)&lds[1][(wm + i) * 512 + lane * 8];
      bhf[i] = *(const bf16x8*)&lds[2][(wn + i) * 512 + lane * 8];
      blf[i] = *(const bf16x8*)&lds[3][(wn + i) * 512 + lane * 8];
    }
    #pragma unroll
    for (int i = 0; i < 4; ++i)
      #pragma unroll
      for (int j = 0; j < 4; ++j) {
        acc[i][j] = __builtin_amdgcn_mfma_f32_16x16x32_bf16(ah[i], bhf[j], acc[i][j], 0, 0, 0);
        acc[i][j] = __builtin_amdgcn_mfma_f32_16x16x32_bf16(ah[i], blf[j], acc[i][j], 0, 0, 0);
        acc[i][j] = __builtin_amdgcn_mfma_f32_16x16x32_bf16(al[i], bhf[j], acc[i][j], 0, 0, 0);
      }
  }

  float* Sp = S + (size_t)bh * 768 * 768;
  #pragma unroll
  for (int i = 0; i < 4; ++i) {
    const int m_b = m0 + (w >> 1) * 64 + i * 16 + lq * 4;
    #pragma unroll
    for (int r = 0; r < 4; ++r) {
      #pragma unroll
      for (int j = 0; j < 4; ++j) {
        const int n = n0 + (w & 1) * 64 + j * 16 + lr;
        Sp[(size_t)(m_b + r) * 768 + n] = acc[i][j][r];
      }
    }
  }
}

// ---------------------------------------------------------------------------
// softmax_1 over rows of 768, output bf16 (RNE)
// ---------------------------------------------------------------------------
__global__ __launch_bounds__(256) void k_softmax1(
    const float* __restrict__ S, const float* __restrict__ temp,
    short* __restrict__ Sout)
{
  const int row = blockIdx.x;
  const float tp = temp[(row / 768) & 3];
  const float* r = S + (size_t)row * 768;
  short* o = Sout + (size_t)row * 768;
  const int t = threadIdx.x;

  float e[3];
  float s = 0.f;
  #pragma unroll
  for (int j = 0; j < 3; ++j) {
    e[j] = expf(r[t + j * 256] * tp);
    s += e[j];
  }
  __shared__ float red[256];
  red[t] = s;
  __syncthreads();
  for (int st = 128; st > 0; st >>= 1) {
    if (t < st) red[t] += red[t + st];
    __syncthreads();
  }
  const float denom = red[0] + 1.0f;
  #pragma unroll
  for (int j = 0; j < 3; ++j) o[t + j * 256] = to_bf16_rne(e[j] / denom);
}

// ---------------------------------------------------------------------------
// O = attn * V via plain-bf16 MFMA. M=768(d), N=1024(n), K=768(e) per bh.
// A = Sbf[d][e], B^T = Vt[n][e]. Epilogue: from_heads scatter into P (fp32).
// ---------------------------------------------------------------------------
__global__ __launch_bounds__(256) void k_av(
    const short* __restrict__ Sbf, const short* __restrict__ Vtb,
    float* __restrict__ P)
{
  __shared__ short lds[2][4096];   // A, B
  const int t = threadIdx.x, lane = t & 63, w = t >> 6;
  const int lr = lane & 15, lq = lane >> 4;
  const int bh = blockIdx.z, head = bh & 3, b = bh >> 2;
  const int m0 = blockIdx.y * 128, n0 = blockIdx.x * 128;
  const short* Sp = Sbf + (size_t)bh * 768 * 768;
  const short* Vp = Vtb + (size_t)bh * 1024 * 768;

  f32x4 acc[4][4] = {};
  const int wm = (w >> 1) * 4, wn = (w & 1) * 4;

  for (int k0 = 0; k0 < 768; k0 += 32) {
    __syncthreads();
    #pragma unroll
    for (int idx = 0; idx < 4; ++idx) {
      const int slot = w * 4 + idx, arr = slot >> 3, sub = slot & 7;
      const short* src = arr ? Vp : Sp;
      const int row0 = arr ? n0 : m0;
      const short* g = src + (size_t)(row0 + sub * 16 + lr) * 768 + k0 + lq * 8;
      gload_lds16(g, &lds[arr][sub * 512]);
    }
    __syncthreads();

    bf16x8 a[4], bb[4];
    #pragma unroll
    for (int i = 0; i < 4; ++i) {
      a[i]  = *(const bf16x8*)&lds[0][(wm + i) * 512 + lane * 8];
      bb[i] = *(const bf16x8*)&lds[1][(wn + i) * 512 + lane * 8];
    }
    #pragma unroll
    for (int i = 0; i < 4; ++i)
      #pragma unroll
      for (int j = 0; j < 4; ++j)
        acc[i][j] = __builtin_amdgcn_mfma_f32_16x16x32_bf16(a[i], bb[j], acc[i][j], 0, 0, 0);
  }

  float* Pb = P + (size_t)b * CDIM * HW;
  #pragma unroll
  for (int i = 0; i < 4; ++i) {
    #pragma unroll
    for (int r = 0; r < 4; ++r) {
      const int d = m0 + (w >> 1) * 64 + i * 16 + lq * 4 + r;
      const int ch = head * 48 + (d >> 4);
      const int fx = (d >> 2) & 3, fy = d & 3;
      float* Pc = Pb + (size_t)ch * HW;
      #pragma unroll
      for (int j = 0; j < 4; ++j) {
        const int n = n0 + (w & 1) * 64 + j * 16 + lr;
        const int h = ((n >> 5) << 2) + fy;
        const int wp = ((n & 31) << 2) + fx;
        Pc[h * 128 + wp] = acc[i][j][r];
      }
    }
  }
}

// ---------------------------------------------------------------------------
extern "C" void kernel_launch(void* const* d_in, const int* in_sizes, int n_in,
                              void* d_out, int out_size, void* d_ws, size_t ws_size,
                              hipStream_t stream) {
  const float* x      = (const float*)d_in[0];
  const float* qkv_w  = (const float*)d_in[1];
  const float* qkv_b  = (const float*)d_in[2];
  const float* dw_w   = (const float*)d_in[3];
  const float* dw_b   = (const float*)d_in[4];
  const float* proj_w = (const float*)d_in[5];
  const float* proj_b = (const float*)d_in[6];
  const float* temp   = (const float*)d_in[7];
  float* out = (float*)d_out;

  float* F = (float*)d_ws;
  const size_t M25 = (size_t)8 * CDIM * HW;      // 25,165,824 floats

  float* tmp = F;                                 // [0, M25) conv scratch
  short* Qhi = (short*)(F + M25);
  short* Qlo = (short*)(F + M25 + M25 / 2);
  short* Khi = (short*)(F + 2 * M25);
  short* Klo = (short*)(F + 2 * M25 + M25 / 2);
  float* Vf  = F + 3 * M25;                       // fp32 V, dead after k_vt
  short* Vtb = (short*)F;                         // [0, M25/2) after tmp dies
  float* Sf  = F + 3 * M25;                       // fp32 S, aliases dead Vf
  short* Sbf = (short*)(F + M25);                 // aliases dead Q
  float* P   = F + 2 * M25;                       // aliases dead K

  for (int sel = 0; sel < 3; ++sel) {
    k_conv1x1<<<dim3(128, 2, 8), 256, 0, stream>>>(
        x, qkv_w + sel * CDIM * CDIM, qkv_b + sel * CDIM, tmp);
    short* dh = (sel == 0) ? Qhi : Khi;
    short* dl = (sel == 0) ? Qlo : Klo;
    k_dw_norm<<<dim3(8 * 4 * 768), 256, 0, stream>>>(
        tmp, dw_w, dw_b, dh, dl, Vf, sel);
  }

  k_vt<<<dim3(16, 12, 32), 256, 0, stream>>>(Vf, Vtb);
  k_qk<<<dim3(6, 6, 32), 256, 0, stream>>>(Qhi, Qlo, Khi, Klo, Sf);
  k_softmax1<<<dim3(8 * 4 * 768), 256, 0, stream>>>(Sf, temp, Sbf);
  k_av<<<dim3(8, 6, 32), 256, 0, stream>>>(Sbf, Vtb, P);
  k_conv1x1<<<dim3(128, 2, 8), 256, 0, stream>>>(P, proj_w, proj_b, out);
}

// Round 3
// 1048.529 us; speedup vs baseline: 2.1294x; 1.5950x over previous
//
#include <hip/hip_runtime.h>

#define HW 16384   // 128*128
#define CDIM 192

typedef short bf16x8 __attribute__((ext_vector_type(8)));
typedef short short8 __attribute__((ext_vector_type(8)));
typedef float f32x4  __attribute__((ext_vector_type(4)));

__device__ inline void gload_lds16(const void* g, void* l) {
  __builtin_amdgcn_global_load_lds(
      (const __attribute__((address_space(1))) void*)g,
      (__attribute__((address_space(3))) void*)l, 16, 0, 0);
}

__device__ inline short to_bf16_rne(float f) {
  unsigned u = __float_as_uint(f);
  unsigned r = u + 0x7fffu + ((u >> 16) & 1u);
  return (short)(r >> 16);
}

__device__ inline void split_bf16(float a, short& hi, short& lo) {
  unsigned u = __float_as_uint(a);
  hi = (short)(u >> 16);                       // truncated high part
  float res = a - __uint_as_float(u & 0xffff0000u);
  lo = (short)(__float_as_uint(res) >> 16);    // residual; pair accurate to ~2^-17
}

// ---------------------------------------------------------------------------
// Split fp32 weight matrix -> hi/lo bf16 (row-major, k contiguous)
// ---------------------------------------------------------------------------
__global__ __launch_bounds__(256) void k_split_w(
    const float* __restrict__ W, short* __restrict__ hi,
    short* __restrict__ lo, int n)
{
  int i = blockIdx.x * 256 + threadIdx.x;
  if (i < n) { short h, l; split_bf16(W[i], h, l); hi[i] = h; lo[i] = l; }
}

// ---------------------------------------------------------------------------
// Split X fp32 [b][192][16384] -> packed hi/lo [b][24][16384][8]
// (8 consecutive k per 16B chunk -> direct MFMA B-fragment layout)
// ---------------------------------------------------------------------------
__global__ __launch_bounds__(256) void k_xsplit(
    const float* __restrict__ X, short* __restrict__ Xhi, short* __restrict__ Xlo)
{
  const int t = threadIdx.x;
  const int b = blockIdx.z, kc = blockIdx.y;
  const int p4 = blockIdx.x * 1024 + t * 4;     // 4 pixels per thread

  float v[8][4];
  #pragma unroll
  for (int kk = 0; kk < 8; ++kk)
    *(float4*)&v[kk][0] = *(const float4*)&X[((size_t)b * CDIM + kc * 8 + kk) * HW + p4];

  #pragma unroll
  for (int i = 0; i < 4; ++i) {
    short8 h8, l8;
    #pragma unroll
    for (int kk = 0; kk < 8; ++kk) {
      short h, l; split_bf16(v[kk][i], h, l);
      h8[kk] = h; l8[kk] = l;
    }
    const size_t o = ((size_t)(b * 24 + kc) * HW + p4 + i) * 8;
    *(short8*)&Xhi[o] = h8;
    *(short8*)&Xlo[o] = l8;
  }
}

// ---------------------------------------------------------------------------
// MFMA 1x1-conv GEMM: Out[bb][m][n] = sum_k W[m][k]*X[bb][k][n] + bias[m]
// W split hi/lo row-major [M][192]; X split packed [bb][24][16384][8].
// m-tile 192 (12 frags, 3 per wave), n-tile 128, BK=32, 3-term split MFMA.
// ---------------------------------------------------------------------------
__global__ __launch_bounds__(256) void k_cmm(
    const short* __restrict__ Xhi, const short* __restrict__ Xlo,
    const short* __restrict__ Whi, const short* __restrict__ Wlo,
    const float* __restrict__ bias, float* __restrict__ Out, int Mtot)
{
  __shared__ short Ah[6144], Al[6144], Bh[4096], Bl[4096];
  const int t = threadIdx.x, lane = t & 63, w = t >> 6;
  const int lr = lane & 15, lq = lane >> 4;
  const int bb = blockIdx.z, m0 = blockIdx.y * 192, n0 = blockIdx.x * 128;
  const short* xh = Xhi + (size_t)bb * 24 * HW * 8;
  const short* xl = Xlo + (size_t)bb * 24 * HW * 8;

  f32x4 acc[3][8] = {};

  for (int k0 = 0; k0 < CDIM; k0 += 32) {
    __syncthreads();
    // A staging: 24 slots (12 hi + 12 lo), 6 per wave
    #pragma unroll
    for (int ii = 0; ii < 6; ++ii) {
      const int id = w * 6 + ii, arr = id / 12, mf = id % 12;
      const short* Wp = arr ? Wlo : Whi;
      const short* g = Wp + (size_t)(m0 + mf * 16 + lr) * CDIM + k0 + lq * 8;
      gload_lds16(g, (arr ? Al : Ah) + mf * 512);
    }
    // B staging: 16 slots (4kc x 2half x 2arr), 4 per wave
    #pragma unroll
    for (int ii = 0; ii < 4; ++ii) {
      const int id = w * 4 + ii, arr = id >> 3, sub = id & 7;
      const int kc = sub >> 1, half = sub & 1;
      const short* src = arr ? xl : xh;
      const short* g = src + ((size_t)(k0 / 8 + kc) * HW + n0 + half * 64 + lane) * 8;
      gload_lds16(g, (arr ? Bl : Bh) + (kc * 128 + half * 64) * 8);
    }
    __syncthreads();

    bf16x8 ahf[3], alf[3];
    #pragma unroll
    for (int mi = 0; mi < 3; ++mi) {
      ahf[mi] = *(const bf16x8*)&Ah[(w * 3 + mi) * 512 + lane * 8];
      alf[mi] = *(const bf16x8*)&Al[(w * 3 + mi) * 512 + lane * 8];
    }
    #pragma unroll
    for (int j = 0; j < 8; ++j) {
      bf16x8 bhf = *(const bf16x8*)&Bh[(lq * 128 + j * 16 + lr) * 8];
      bf16x8 blf = *(const bf16x8*)&Bl[(lq * 128 + j * 16 + lr) * 8];
      #pragma unroll
      for (int mi = 0; mi < 3; ++mi) {
        acc[mi][j] = __builtin_amdgcn_mfma_f32_16x16x32_bf16(ahf[mi], bhf, acc[mi][j], 0, 0, 0);
        acc[mi][j] = __builtin_amdgcn_mfma_f32_16x16x32_bf16(ahf[mi], blf, acc[mi][j], 0, 0, 0);
        acc[mi][j] = __builtin_amdgcn_mfma_f32_16x16x32_bf16(alf[mi], bhf, acc[mi][j], 0, 0, 0);
      }
    }
  }

  #pragma unroll
  for (int mi = 0; mi < 3; ++mi) {
    #pragma unroll
    for (int r = 0; r < 4; ++r) {
      const int m = m0 + (w * 3 + mi) * 16 + lq * 4 + r;
      const float bv = bias[m];
      #pragma unroll
      for (int j = 0; j < 8; ++j) {
        const int n = n0 + j * 16 + lr;
        Out[((size_t)bb * Mtot + m) * HW + n] = acc[mi][j][r] + bv;
      }
    }
  }
}

// ---------------------------------------------------------------------------
// Depthwise 3x3 + bias + to_heads + norm, one block per (local-b, gch).
// tmp fp32 [2][576][HW] -> Q hi/lo split | K bf16 | Vt bf16 [bh][n][768].
// ---------------------------------------------------------------------------
__global__ __launch_bounds__(256) void k_dw(
    const float* __restrict__ tmp,
    const float* __restrict__ dww, const float* __restrict__ dwb,
    short* __restrict__ Qhi, short* __restrict__ Qlo,
    short* __restrict__ Kb, short* __restrict__ Vt, int b0)
{
  __shared__ float dwout[16 * 1024];
  __shared__ float sums[16][64];
  __shared__ float rednorm[16];

  const int gc = blockIdx.x, lb = blockIdx.y, b = b0 + lb;
  const int sel = gc / CDIM, chl = gc % CDIM;
  const int head = chl / 48, c = chl % 48;
  const float* img = tmp + ((size_t)lb * 576 + gc) * HW;
  const int t = threadIdx.x;

  float wgt[9];
  #pragma unroll
  for (int i = 0; i < 9; ++i) wgt[i] = dww[gc * 9 + i];
  const float bias = dwb[gc];

  const int fy = (t >> 5) & 3;           // fixed per thread
  float sqp[4] = {0.f, 0.f, 0.f, 0.f};

  for (int i = 0; i < 16; ++i) {
    const int p4 = i * 1024 + t * 4;
    const int h = p4 >> 7, w0 = p4 & 127;
    float win[3][6];
    #pragma unroll
    for (int dy = 0; dy < 3; ++dy) {
      const int r = h + dy - 1;
      if (r < 0 || r > 127) {
        #pragma unroll
        for (int q = 0; q < 6; ++q) win[dy][q] = 0.f;
      } else {
        const float* rp = img + r * 128 + w0;
        float4 c4 = *(const float4*)rp;
        win[dy][0] = (w0 > 0) ? rp[-1] : 0.f;
        win[dy][1] = c4.x; win[dy][2] = c4.y; win[dy][3] = c4.z; win[dy][4] = c4.w;
        win[dy][5] = (w0 < 124) ? rp[4] : 0.f;
      }
    }
    const int n = (h >> 2) * 32 + (w0 >> 2);
    #pragma unroll
    for (int fx = 0; fx < 4; ++fx) {
      float a = bias;
      #pragma unroll
      for (int dy = 0; dy < 3; ++dy)
        #pragma unroll
        for (int dx = 0; dx < 3; ++dx)
          a = fmaf(win[dy][fx + dx], wgt[dy * 3 + dx], a);
      sqp[fx] = fmaf(a, a, sqp[fx]);
      dwout[(fx * 4 + fy) * 1024 + n] = a;
    }
  }

  if (sel < 2) {
    const int slot = (t & 31) | (((t >> 7) & 1) << 5);
    #pragma unroll
    for (int fx = 0; fx < 4; ++fx) sums[fx * 4 + fy][slot] = sqp[fx];
    __syncthreads();
    const int row = t >> 4, i16 = t & 15;
    float v = sums[row][i16] + sums[row][i16 + 16] + sums[row][i16 + 32] + sums[row][i16 + 48];
    __syncthreads();
    sums[row][i16] = v;
    __syncthreads();
    if (t < 16) {
      float s = 0.f;
      #pragma unroll
      for (int j = 0; j < 16; ++j) s += sums[t][j];
      rednorm[t] = fmaxf(sqrtf(s), 1e-12f);
    }
  }
  __syncthreads();

  if (sel == 2) {      // V -> transposed bf16 [bh][n][768]
    #pragma unroll
    for (int j = 0; j < 4; ++j) {
      const int n = t + j * 256;
      short8 v0, v1;
      #pragma unroll
      for (int rr = 0; rr < 8; ++rr) v0[rr] = to_bf16_rne(dwout[rr * 1024 + n]);
      #pragma unroll
      for (int rr = 0; rr < 8; ++rr) v1[rr] = to_bf16_rne(dwout[(rr + 8) * 1024 + n]);
      const size_t o = ((size_t)(b * 4 + head) * 1024 + n) * 768 + c * 16;
      *(short8*)&Vt[o] = v0;
      *(short8*)&Vt[o + 8] = v1;
    }
    return;
  }

  #pragma unroll
  for (int rr = 0; rr < 16; ++rr) {
    const float inv = 1.0f / rednorm[rr];
    const size_t rowoff = ((size_t)(b * 4 + head) * 768 + c * 16 + rr) * 1024;
    #pragma unroll
    for (int j = 0; j < 2; ++j) {
      const int n2 = j * 512 + t * 2;
      const float v0 = dwout[rr * 1024 + n2] * inv;
      const float v1 = dwout[rr * 1024 + n2 + 1] * inv;
      if (sel == 0) {
        short h0, l0, h1, l1;
        split_bf16(v0, h0, l0); split_bf16(v1, h1, l1);
        *(unsigned*)&Qhi[rowoff + n2] = ((unsigned)(unsigned short)h1 << 16) | (unsigned short)h0;
        *(unsigned*)&Qlo[rowoff + n2] = ((unsigned)(unsigned short)l1 << 16) | (unsigned short)l0;
      } else {
        *(unsigned*)&Kb[rowoff + n2] =
            ((unsigned)(unsigned short)to_bf16_rne(v1) << 16) | (unsigned short)to_bf16_rne(v0);
      }
    }
  }
}

// ---------------------------------------------------------------------------
// S = Q*K^T via MFMA, 2-term (Qhi+Qlo)*Kbf16. M=N=768, K=1024 per bh.
// ---------------------------------------------------------------------------
__global__ __launch_bounds__(256) void k_qk(
    const short* __restrict__ Qhi, const short* __restrict__ Qlo,
    const short* __restrict__ Kbf, float* __restrict__ S)
{
  __shared__ short lds[3][4096];   // Q_hi, Q_lo, K
  const int t = threadIdx.x, lane = t & 63, w = t >> 6;
  const int lr = lane & 15, lq = lane >> 4;
  const int bh = blockIdx.z, m0 = blockIdx.y * 128, n0 = blockIdx.x * 128;
  const size_t base = (size_t)bh * 768 * 1024;

  f32x4 acc[4][4] = {};
  const int wm = (w >> 1) * 4, wn = (w & 1) * 4;

  for (int k0 = 0; k0 < 1024; k0 += 32) {
    __syncthreads();
    #pragma unroll
    for (int ii = 0; ii < 6; ++ii) {
      const int id = w * 6 + ii, arr = id >> 3, sub = id & 7;
      const short* src = (arr == 0) ? Qhi : (arr == 1) ? Qlo : Kbf;
      const int row0 = (arr < 2) ? m0 : n0;
      const short* g = src + base + (size_t)(row0 + sub * 16 + lr) * 1024 + k0 + lq * 8;
      gload_lds16(g, &lds[arr][sub * 512]);
    }
    __syncthreads();

    bf16x8 ah[4], al[4], bf[4];
    #pragma unroll
    for (int i = 0; i < 4; ++i) {
      ah[i] = *(const bf16x8*)&lds[0][(wm + i) * 512 + lane * 8];
      al[i] = *(const bf16x8*)&lds[1][(wm + i) * 512 + lane * 8];
      bf[i] = *(const bf16x8*)&lds[2][(wn + i) * 512 + lane * 8];
    }
    #pragma unroll
    for (int i = 0; i < 4; ++i)
      #pragma unroll
      for (int j = 0; j < 4; ++j) {
        acc[i][j] = __builtin_amdgcn_mfma_f32_16x16x32_bf16(ah[i], bf[j], acc[i][j], 0, 0, 0);
        acc[i][j] = __builtin_amdgcn_mfma_f32_16x16x32_bf16(al[i], bf[j], acc[i][j], 0, 0, 0);
      }
  }

  float* Sp = S + (size_t)bh * 768 * 768;
  #pragma unroll
  for (int i = 0; i < 4; ++i) {
    const int m_b = m0 + (w >> 1) * 64 + i * 16 + lq * 4;
    #pragma unroll
    for (int r = 0; r < 4; ++r) {
      #pragma unroll
      for (int j = 0; j < 4; ++j) {
        const int n = n0 + (w & 1) * 64 + j * 16 + lr;
        Sp[(size_t)(m_b + r) * 768 + n] = acc[i][j][r];
      }
    }
  }
}

// ---------------------------------------------------------------------------
// softmax_1 over rows of 768, output bf16 (RNE)
// ---------------------------------------------------------------------------
__global__ __launch_bounds__(256) void k_softmax1(
    const float* __restrict__ S, const float* __restrict__ temp,
    short* __restrict__ Sout)
{
  const int row = blockIdx.x;
  const float tp = temp[(row / 768) & 3];
  const float* r = S + (size_t)row * 768;
  short* o = Sout + (size_t)row * 768;
  const int t = threadIdx.x;

  float e[3];
  float s = 0.f;
  #pragma unroll
  for (int j = 0; j < 3; ++j) {
    e[j] = expf(r[t + j * 256] * tp);
    s += e[j];
  }
  __shared__ float red[256];
  red[t] = s;
  __syncthreads();
  for (int st = 128; st > 0; st >>= 1) {
    if (t < st) red[t] += red[t + st];
    __syncthreads();
  }
  const float denom = red[0] + 1.0f;
  #pragma unroll
  for (int j = 0; j < 3; ++j) o[t + j * 256] = to_bf16_rne(e[j] / denom);
}

// ---------------------------------------------------------------------------
// O = attn * V via bf16 MFMA; epilogue: from_heads scatter as SPLIT-PACKED P
// Phi/Plo [b][24][16384][8] ready for the proj k_cmm.
// ---------------------------------------------------------------------------
__global__ __launch_bounds__(256) void k_av(
    const short* __restrict__ Sbf, const short* __restrict__ Vtb,
    short* __restrict__ Phi, short* __restrict__ Plo)
{
  __shared__ short lds[2][4096];
  const int t = threadIdx.x, lane = t & 63, w = t >> 6;
  const int lr = lane & 15, lq = lane >> 4;
  const int bh = blockIdx.z, head = bh & 3, b = bh >> 2;
  const int m0 = blockIdx.y * 128, n0 = blockIdx.x * 128;
  const short* Sp = Sbf + (size_t)bh * 768 * 768;
  const short* Vp = Vtb + (size_t)bh * 1024 * 768;

  f32x4 acc[4][4] = {};
  const int wm = (w >> 1) * 4, wn = (w & 1) * 4;

  for (int k0 = 0; k0 < 768; k0 += 32) {
    __syncthreads();
    #pragma unroll
    for (int idx = 0; idx < 4; ++idx) {
      const int slot = w * 4 + idx, arr = slot >> 3, sub = slot & 7;
      const short* src = arr ? Vp : Sp;
      const int row0 = arr ? n0 : m0;
      const short* g = src + (size_t)(row0 + sub * 16 + lr) * 768 + k0 + lq * 8;
      gload_lds16(g, &lds[arr][sub * 512]);
    }
    __syncthreads();

    bf16x8 a[4], bb4[4];
    #pragma unroll
    for (int i = 0; i < 4; ++i) {
      a[i]   = *(const bf16x8*)&lds[0][(wm + i) * 512 + lane * 8];
      bb4[i] = *(const bf16x8*)&lds[1][(wn + i) * 512 + lane * 8];
    }
    #pragma unroll
    for (int i = 0; i < 4; ++i)
      #pragma unroll
      for (int j = 0; j < 4; ++j)
        acc[i][j] = __builtin_amdgcn_mfma_f32_16x16x32_bf16(a[i], bb4[j], acc[i][j], 0, 0, 0);
  }

  #pragma unroll
  for (int i = 0; i < 4; ++i) {
    #pragma unroll
    for (int r = 0; r < 4; ++r) {
      const int d = m0 + (w >> 1) * 64 + i * 16 + lq * 4 + r;
      const int ch = head * 48 + (d >> 4);
      const int fx = (d >> 2) & 3, fy = d & 3;
      #pragma unroll
      for (int j = 0; j < 4; ++j) {
        const int n = n0 + (w & 1) * 64 + j * 16 + lr;
        const int h = ((n >> 5) << 2) + fy;
        const int wp = ((n & 31) << 2) + fx;
        const size_t o = ((size_t)(b * 24 + (ch >> 3)) * HW + h * 128 + wp) * 8 + (ch & 7);
        short hi, lo; split_bf16(acc[i][j][r], hi, lo);
        Phi[o] = hi;
        Plo[o] = lo;
      }
    }
  }
}

// ---------------------------------------------------------------------------
extern "C" void kernel_launch(void* const* d_in, const int* in_sizes, int n_in,
                              void* d_out, int out_size, void* d_ws, size_t ws_size,
                              hipStream_t stream) {
  const float* x      = (const float*)d_in[0];
  const float* qkv_w  = (const float*)d_in[1];
  const float* qkv_b  = (const float*)d_in[2];
  const float* dw_w   = (const float*)d_in[3];
  const float* dw_b   = (const float*)d_in[4];
  const float* proj_w = (const float*)d_in[5];
  const float* proj_b = (const float*)d_in[6];
  const float* temp   = (const float*)d_in[7];
  float* out = (float*)d_out;

  float* F = (float*)d_ws;
  const size_t M25 = (size_t)8 * CDIM * HW;      // 25,165,824 elements
  // Layout (bytes): [0,100.7M) Q hi/lo -> later P hi/lo ; [100.7,151M) Kb ;
  // [151,201.3M) Vt ; [201.3,302M) X hi/lo -> later S fp32 ; [302,377.5M) tmp
  // fp32 (2 batches) -> later Sbf ; [377.5,378.1M) W splits.
  short* Qhi = (short*)F;
  short* Qlo = Qhi + M25;
  short* Kb  = (short*)(F + M25);
  short* Vt  = Kb + M25;
  short* Xhi = (short*)(F + 2 * M25);
  short* Xlo = Xhi + M25;
  float* tmpf = F + 3 * M25;                      // 18,874,368 floats
  short* WS   = (short*)(F + 3 * M25 + 18874368);
  short* Wq_hi = WS;             // 576*192
  short* Wq_lo = WS + 110592;
  short* Wp_hi = WS + 221184;    // 192*192
  short* Wp_lo = WS + 258048;
  float* Sf  = F + 2 * M25;                       // alias X (dead after convs)
  short* Sbf = (short*)tmpf;                      // alias tmp (dead after dw)
  short* Phi = Qhi;                               // alias Q (dead after qk)
  short* Plo = Qlo;

  k_split_w<<<dim3(432), 256, 0, stream>>>(qkv_w, Wq_hi, Wq_lo, 110592);
  k_split_w<<<dim3(144), 256, 0, stream>>>(proj_w, Wp_hi, Wp_lo, 36864);
  k_xsplit<<<dim3(16, 24, 8), 256, 0, stream>>>(x, Xhi, Xlo);

  for (int b0 = 0; b0 < 8; b0 += 2) {
    k_cmm<<<dim3(128, 3, 2), 256, 0, stream>>>(
        Xhi + (size_t)b0 * 24 * HW * 8, Xlo + (size_t)b0 * 24 * HW * 8,
        Wq_hi, Wq_lo, qkv_b, tmpf, 576);
    k_dw<<<dim3(576, 2), 256, 0, stream>>>(
        tmpf, dw_w, dw_b, Qhi, Qlo, Kb, Vt, b0);
  }

  k_qk<<<dim3(6, 6, 32), 256, 0, stream>>>(Qhi, Qlo, Kb, Sf);
  k_softmax1<<<dim3(8 * 4 * 768), 256, 0, stream>>>(Sf, temp, Sbf);
  k_av<<<dim3(8, 6, 32), 256, 0, stream>>>(Sbf, Vt, Phi, Plo);
  k_cmm<<<dim3(128, 1, 8), 256, 0, stream>>>(
      Phi, Plo, Wp_hi, Wp_lo, proj_b, out, 192);
}

// Round 4
// 998.498 us; speedup vs baseline: 2.2361x; 1.0501x over previous
//
#include <hip/hip_runtime.h>

#define HW 16384   // 128*128
#define CDIM 192

typedef short bf16x8 __attribute__((ext_vector_type(8)));
typedef short short8 __attribute__((ext_vector_type(8)));
typedef float f32x4  __attribute__((ext_vector_type(4)));

__device__ inline void gload_lds16(const void* g, void* l) {
  __builtin_amdgcn_global_load_lds(
      (const __attribute__((address_space(1))) void*)g,
      (__attribute__((address_space(3))) void*)l, 16, 0, 0);
}

__device__ inline short to_bf16_rne(float f) {
  unsigned u = __float_as_uint(f);
  unsigned r = u + 0x7fffu + ((u >> 16) & 1u);
  return (short)(r >> 16);
}

__device__ inline void split_bf16(float a, short& hi, short& lo) {
  unsigned u = __float_as_uint(a);
  hi = (short)(u >> 16);                       // truncated high part
  float res = a - __uint_as_float(u & 0xffff0000u);
  lo = (short)(__float_as_uint(res) >> 16);    // residual; pair accurate to ~2^-17
}

// ---------------------------------------------------------------------------
__global__ __launch_bounds__(256) void k_zero(float* __restrict__ p, int n) {
  int i = blockIdx.x * 256 + threadIdx.x;
  if (i < n) p[i] = 0.f;
}

// ---------------------------------------------------------------------------
// Split fp32 weight matrix -> hi/lo bf16 (row-major, k contiguous)
// ---------------------------------------------------------------------------
__global__ __launch_bounds__(256) void k_split_w(
    const float* __restrict__ W, short* __restrict__ hi,
    short* __restrict__ lo, int n)
{
  int i = blockIdx.x * 256 + threadIdx.x;
  if (i < n) { short h, l; split_bf16(W[i], h, l); hi[i] = h; lo[i] = l; }
}

// ---------------------------------------------------------------------------
// Split X fp32 [b][192][16384] -> packed hi/lo [b][24][16384][8]
// ---------------------------------------------------------------------------
__global__ __launch_bounds__(256) void k_xsplit(
    const float* __restrict__ X, short* __restrict__ Xhi, short* __restrict__ Xlo)
{
  const int t = threadIdx.x;
  const int b = blockIdx.z, kc = blockIdx.y;
  const int p4 = blockIdx.x * 1024 + t * 4;

  float v[8][4];
  #pragma unroll
  for (int kk = 0; kk < 8; ++kk)
    *(float4*)&v[kk][0] = *(const float4*)&X[((size_t)b * CDIM + kc * 8 + kk) * HW + p4];

  #pragma unroll
  for (int i = 0; i < 4; ++i) {
    short8 h8, l8;
    #pragma unroll
    for (int kk = 0; kk < 8; ++kk) {
      short h, l; split_bf16(v[kk][i], h, l);
      h8[kk] = h; l8[kk] = l;
    }
    const size_t o = ((size_t)(b * 24 + kc) * HW + p4 + i) * 8;
    *(short8*)&Xhi[o] = h8;
    *(short8*)&Xlo[o] = l8;
  }
}

// ---------------------------------------------------------------------------
// MFMA 1x1-conv GEMM (unchanged from round 3)
// ---------------------------------------------------------------------------
__global__ __launch_bounds__(256) void k_cmm(
    const short* __restrict__ Xhi, const short* __restrict__ Xlo,
    const short* __restrict__ Whi, const short* __restrict__ Wlo,
    const float* __restrict__ bias, float* __restrict__ Out, int Mtot)
{
  __shared__ short Ah[6144], Al[6144], Bh[4096], Bl[4096];
  const int t = threadIdx.x, lane = t & 63, w = t >> 6;
  const int lr = lane & 15, lq = lane >> 4;
  const int bb = blockIdx.z, m0 = blockIdx.y * 192, n0 = blockIdx.x * 128;
  const short* xh = Xhi + (size_t)bb * 24 * HW * 8;
  const short* xl = Xlo + (size_t)bb * 24 * HW * 8;

  f32x4 acc[3][8] = {};

  for (int k0 = 0; k0 < CDIM; k0 += 32) {
    __syncthreads();
    #pragma unroll
    for (int ii = 0; ii < 6; ++ii) {
      const int id = w * 6 + ii, arr = id / 12, mf = id % 12;
      const short* Wp = arr ? Wlo : Whi;
      const short* g = Wp + (size_t)(m0 + mf * 16 + lr) * CDIM + k0 + lq * 8;
      gload_lds16(g, (arr ? Al : Ah) + mf * 512);
    }
    #pragma unroll
    for (int ii = 0; ii < 4; ++ii) {
      const int id = w * 4 + ii, arr = id >> 3, sub = id & 7;
      const int kc = sub >> 1, half = sub & 1;
      const short* src = arr ? xl : xh;
      const short* g = src + ((size_t)(k0 / 8 + kc) * HW + n0 + half * 64 + lane) * 8;
      gload_lds16(g, (arr ? Bl : Bh) + (kc * 128 + half * 64) * 8);
    }
    __syncthreads();

    bf16x8 ahf[3], alf[3];
    #pragma unroll
    for (int mi = 0; mi < 3; ++mi) {
      ahf[mi] = *(const bf16x8*)&Ah[(w * 3 + mi) * 512 + lane * 8];
      alf[mi] = *(const bf16x8*)&Al[(w * 3 + mi) * 512 + lane * 8];
    }
    #pragma unroll
    for (int j = 0; j < 8; ++j) {
      bf16x8 bhf = *(const bf16x8*)&Bh[(lq * 128 + j * 16 + lr) * 8];
      bf16x8 blf = *(const bf16x8*)&Bl[(lq * 128 + j * 16 + lr) * 8];
      #pragma unroll
      for (int mi = 0; mi < 3; ++mi) {
        acc[mi][j] = __builtin_amdgcn_mfma_f32_16x16x32_bf16(ahf[mi], bhf, acc[mi][j], 0, 0, 0);
        acc[mi][j] = __builtin_amdgcn_mfma_f32_16x16x32_bf16(ahf[mi], blf, acc[mi][j], 0, 0, 0);
        acc[mi][j] = __builtin_amdgcn_mfma_f32_16x16x32_bf16(alf[mi], bhf, acc[mi][j], 0, 0, 0);
      }
    }
  }

  #pragma unroll
  for (int mi = 0; mi < 3; ++mi) {
    #pragma unroll
    for (int r = 0; r < 4; ++r) {
      const int m = m0 + (w * 3 + mi) * 16 + lq * 4 + r;
      const float bv = bias[m];
      #pragma unroll
      for (int j = 0; j < 8; ++j) {
        const int n = n0 + j * 16 + lr;
        Out[((size_t)bb * Mtot + m) * HW + n] = acc[mi][j][r] + bv;
      }
    }
  }
}

// ---------------------------------------------------------------------------
// Depthwise 3x3 + bias + to_heads + norm (unchanged from round 3)
// ---------------------------------------------------------------------------
__global__ __launch_bounds__(256) void k_dw(
    const float* __restrict__ tmp,
    const float* __restrict__ dww, const float* __restrict__ dwb,
    short* __restrict__ Qhi, short* __restrict__ Qlo,
    short* __restrict__ Kb, short* __restrict__ Vt, int b0)
{
  __shared__ float dwout[16 * 1024];
  __shared__ float sums[16][64];
  __shared__ float rednorm[16];

  const int gc = blockIdx.x, lb = blockIdx.y, b = b0 + lb;
  const int sel = gc / CDIM, chl = gc % CDIM;
  const int head = chl / 48, c = chl % 48;
  const float* img = tmp + ((size_t)lb * 576 + gc) * HW;
  const int t = threadIdx.x;

  float wgt[9];
  #pragma unroll
  for (int i = 0; i < 9; ++i) wgt[i] = dww[gc * 9 + i];
  const float bias = dwb[gc];

  const int fy = (t >> 5) & 3;
  float sqp[4] = {0.f, 0.f, 0.f, 0.f};

  for (int i = 0; i < 16; ++i) {
    const int p4 = i * 1024 + t * 4;
    const int h = p4 >> 7, w0 = p4 & 127;
    float win[3][6];
    #pragma unroll
    for (int dy = 0; dy < 3; ++dy) {
      const int r = h + dy - 1;
      if (r < 0 || r > 127) {
        #pragma unroll
        for (int q = 0; q < 6; ++q) win[dy][q] = 0.f;
      } else {
        const float* rp = img + r * 128 + w0;
        float4 c4 = *(const float4*)rp;
        win[dy][0] = (w0 > 0) ? rp[-1] : 0.f;
        win[dy][1] = c4.x; win[dy][2] = c4.y; win[dy][3] = c4.z; win[dy][4] = c4.w;
        win[dy][5] = (w0 < 124) ? rp[4] : 0.f;
      }
    }
    const int n = (h >> 2) * 32 + (w0 >> 2);
    #pragma unroll
    for (int fx = 0; fx < 4; ++fx) {
      float a = bias;
      #pragma unroll
      for (int dy = 0; dy < 3; ++dy)
        #pragma unroll
        for (int dx = 0; dx < 3; ++dx)
          a = fmaf(win[dy][fx + dx], wgt[dy * 3 + dx], a);
      sqp[fx] = fmaf(a, a, sqp[fx]);
      dwout[(fx * 4 + fy) * 1024 + n] = a;
    }
  }

  if (sel < 2) {
    const int slot = (t & 31) | (((t >> 7) & 1) << 5);
    #pragma unroll
    for (int fx = 0; fx < 4; ++fx) sums[fx * 4 + fy][slot] = sqp[fx];
    __syncthreads();
    const int row = t >> 4, i16 = t & 15;
    float v = sums[row][i16] + sums[row][i16 + 16] + sums[row][i16 + 32] + sums[row][i16 + 48];
    __syncthreads();
    sums[row][i16] = v;
    __syncthreads();
    if (t < 16) {
      float s = 0.f;
      #pragma unroll
      for (int j = 0; j < 16; ++j) s += sums[t][j];
      rednorm[t] = fmaxf(sqrtf(s), 1e-12f);
    }
  }
  __syncthreads();

  if (sel == 2) {
    #pragma unroll
    for (int j = 0; j < 4; ++j) {
      const int n = t + j * 256;
      short8 v0, v1;
      #pragma unroll
      for (int rr = 0; rr < 8; ++rr) v0[rr] = to_bf16_rne(dwout[rr * 1024 + n]);
      #pragma unroll
      for (int rr = 0; rr < 8; ++rr) v1[rr] = to_bf16_rne(dwout[(rr + 8) * 1024 + n]);
      const size_t o = ((size_t)(b * 4 + head) * 1024 + n) * 768 + c * 16;
      *(short8*)&Vt[o] = v0;
      *(short8*)&Vt[o + 8] = v1;
    }
    return;
  }

  #pragma unroll
  for (int rr = 0; rr < 16; ++rr) {
    const float inv = 1.0f / rednorm[rr];
    const size_t rowoff = ((size_t)(b * 4 + head) * 768 + c * 16 + rr) * 1024;
    #pragma unroll
    for (int j = 0; j < 2; ++j) {
      const int n2 = j * 512 + t * 2;
      const float v0 = dwout[rr * 1024 + n2] * inv;
      const float v1 = dwout[rr * 1024 + n2 + 1] * inv;
      if (sel == 0) {
        short h0, l0, h1, l1;
        split_bf16(v0, h0, l0); split_bf16(v1, h1, l1);
        *(unsigned*)&Qhi[rowoff + n2] = ((unsigned)(unsigned short)h1 << 16) | (unsigned short)h0;
        *(unsigned*)&Qlo[rowoff + n2] = ((unsigned)(unsigned short)l1 << 16) | (unsigned short)l0;
      } else {
        *(unsigned*)&Kb[rowoff + n2] =
            ((unsigned)(unsigned short)to_bf16_rne(v1) << 16) | (unsigned short)to_bf16_rne(v0);
      }
    }
  }
}

// ---------------------------------------------------------------------------
// E = exp(Q*K^T * temp) via 2-term MFMA, BK=64, fused rowsum atomics.
// Writes E bf16 [bh][768][768]; Sums[bh][768] += partial row sums (fp32).
// XCD-aware remap: each XCD handles 4 contiguous bh (L2 locality).
// ---------------------------------------------------------------------------
__global__ __launch_bounds__(256) void k_qk(
    const short* __restrict__ Qhi, const short* __restrict__ Qlo,
    const short* __restrict__ Kbf, const float* __restrict__ temp,
    short* __restrict__ E, float* __restrict__ Sums)
{
  __shared__ short lds[3][8192];   // 16KB each: 16 slots (8 rowgrp x 2 kc)
  const int t = threadIdx.x, lane = t & 63, w = t >> 6;
  const int lr = lane & 15, lq = lane >> 4;

  const int flat = blockIdx.x + 6 * blockIdx.y + 36 * blockIdx.z;
  const int g = (flat & 7) * 144 + (flat >> 3);     // bijection on [0,1152)
  const int bh = g / 36, tile = g % 36;
  const int m0 = (tile / 6) * 128, n0 = (tile % 6) * 128;
  const size_t base = (size_t)bh * 768 * 1024;

  f32x4 acc[4][4] = {};
  const int wm = (w >> 1) * 4, wn = (w & 1) * 4;

  for (int k0 = 0; k0 < 1024; k0 += 64) {
    __syncthreads();
    #pragma unroll
    for (int ii = 0; ii < 12; ++ii) {
      const int id = w * 12 + ii;                 // 0..47
      const int arr = id >> 4, sub = id & 15;
      const int s = sub >> 1, kc = sub & 1;
      const short* src = (arr == 0) ? Qhi : (arr == 1) ? Qlo : Kbf;
      const int row0 = (arr < 2) ? m0 : n0;
      const short* gp = src + base + (size_t)(row0 + s * 16 + lr) * 1024 + k0 + kc * 32 + lq * 8;
      gload_lds16(gp, &lds[arr][(s * 2 + kc) * 512]);
    }
    __syncthreads();

    #pragma unroll
    for (int kc = 0; kc < 2; ++kc) {
      bf16x8 ah[4], al[4], bf_[4];
      #pragma unroll
      for (int i = 0; i < 4; ++i) {
        ah[i]  = *(const bf16x8*)&lds[0][((wm + i) * 2 + kc) * 512 + lane * 8];
        al[i]  = *(const bf16x8*)&lds[1][((wm + i) * 2 + kc) * 512 + lane * 8];
        bf_[i] = *(const bf16x8*)&lds[2][((wn + i) * 2 + kc) * 512 + lane * 8];
      }
      #pragma unroll
      for (int i = 0; i < 4; ++i)
        #pragma unroll
        for (int j = 0; j < 4; ++j) {
          acc[i][j] = __builtin_amdgcn_mfma_f32_16x16x32_bf16(ah[i], bf_[j], acc[i][j], 0, 0, 0);
          acc[i][j] = __builtin_amdgcn_mfma_f32_16x16x32_bf16(al[i], bf_[j], acc[i][j], 0, 0, 0);
        }
    }
  }

  const float tp = temp[bh & 3];
  float* Srow = Sums + bh * 768;
  short* Ep = E + (size_t)bh * 768 * 768;
  #pragma unroll
  for (int i = 0; i < 4; ++i) {
    #pragma unroll
    for (int r = 0; r < 4; ++r) {
      const int m = m0 + (w >> 1) * 64 + i * 16 + lq * 4 + r;
      short* erow = Ep + (size_t)m * 768 + n0 + (w & 1) * 64;
      float rs = 0.f;
      #pragma unroll
      for (int j = 0; j < 4; ++j) {
        const float e = expf(acc[i][j][r] * tp);
        rs += e;
        erow[j * 16 + lr] = to_bf16_rne(e);
      }
      rs += __shfl_xor(rs, 1);
      rs += __shfl_xor(rs, 2);
      rs += __shfl_xor(rs, 4);
      rs += __shfl_xor(rs, 8);
      if (lr == 0) atomicAdd(&Srow[m], rs);
    }
  }
}

// ---------------------------------------------------------------------------
// O = (E * V) / (sum+1) via bf16 MFMA, BK=64; epilogue scatters split-packed
// P hi/lo [b][24][16384][8] for the proj k_cmm.
// ---------------------------------------------------------------------------
__global__ __launch_bounds__(256) void k_av(
    const short* __restrict__ Ebf, const short* __restrict__ Vtb,
    const float* __restrict__ Sums,
    short* __restrict__ Phi, short* __restrict__ Plo)
{
  __shared__ short lds[2][8192];   // 16 slots each
  const int t = threadIdx.x, lane = t & 63, w = t >> 6;
  const int lr = lane & 15, lq = lane >> 4;

  const int flat = blockIdx.x + 8 * blockIdx.y + 48 * blockIdx.z;
  const int g = (flat & 7) * 192 + (flat >> 3);     // bijection on [0,1536)
  const int bh = g / 48, tile = g % 48;
  const int m0 = (tile / 8) * 128, n0 = (tile % 8) * 128;
  const int head = bh & 3, b = bh >> 2;
  const short* Sp = Ebf + (size_t)bh * 768 * 768;
  const short* Vp = Vtb + (size_t)bh * 1024 * 768;

  f32x4 acc[4][4] = {};
  const int wm = (w >> 1) * 4, wn = (w & 1) * 4;

  for (int k0 = 0; k0 < 768; k0 += 64) {
    __syncthreads();
    #pragma unroll
    for (int ii = 0; ii < 8; ++ii) {
      const int id = w * 8 + ii;                  // 0..31
      const int arr = id >> 4, sub = id & 15;
      const int s = sub >> 1, kc = sub & 1;
      const short* src = arr ? Vp : Sp;
      const int row0 = arr ? n0 : m0;
      const short* gp = src + (size_t)(row0 + s * 16 + lr) * 768 + k0 + kc * 32 + lq * 8;
      gload_lds16(gp, &lds[arr][(s * 2 + kc) * 512]);
    }
    __syncthreads();

    #pragma unroll
    for (int kc = 0; kc < 2; ++kc) {
      bf16x8 a[4], bb4[4];
      #pragma unroll
      for (int i = 0; i < 4; ++i) {
        a[i]   = *(const bf16x8*)&lds[0][((wm + i) * 2 + kc) * 512 + lane * 8];
        bb4[i] = *(const bf16x8*)&lds[1][((wn + i) * 2 + kc) * 512 + lane * 8];
      }
      #pragma unroll
      for (int i = 0; i < 4; ++i)
        #pragma unroll
        for (int j = 0; j < 4; ++j)
          acc[i][j] = __builtin_amdgcn_mfma_f32_16x16x32_bf16(a[i], bb4[j], acc[i][j], 0, 0, 0);
    }
  }

  const float* Srow = Sums + bh * 768;
  #pragma unroll
  for (int i = 0; i < 4; ++i) {
    #pragma unroll
    for (int r = 0; r < 4; ++r) {
      const int d = m0 + (w >> 1) * 64 + i * 16 + lq * 4 + r;
      const float inv = 1.0f / (Srow[d] + 1.0f);
      const int ch = head * 48 + (d >> 4);
      const int fx = (d >> 2) & 3, fy = d & 3;
      #pragma unroll
      for (int j = 0; j < 4; ++j) {
        const int n = n0 + (w & 1) * 64 + j * 16 + lr;
        const int h = ((n >> 5) << 2) + fy;
        const int wp = ((n & 31) << 2) + fx;
        const size_t o = ((size_t)(b * 24 + (ch >> 3)) * HW + h * 128 + wp) * 8 + (ch & 7);
        short hi, lo; split_bf16(acc[i][j][r] * inv, hi, lo);
        Phi[o] = hi;
        Plo[o] = lo;
      }
    }
  }
}

// ---------------------------------------------------------------------------
extern "C" void kernel_launch(void* const* d_in, const int* in_sizes, int n_in,
                              void* d_out, int out_size, void* d_ws, size_t ws_size,
                              hipStream_t stream) {
  const float* x      = (const float*)d_in[0];
  const float* qkv_w  = (const float*)d_in[1];
  const float* qkv_b  = (const float*)d_in[2];
  const float* dw_w   = (const float*)d_in[3];
  const float* dw_b   = (const float*)d_in[4];
  const float* proj_w = (const float*)d_in[5];
  const float* proj_b = (const float*)d_in[6];
  const float* temp   = (const float*)d_in[7];
  float* out = (float*)d_out;

  float* F = (float*)d_ws;
  const size_t M25 = (size_t)8 * CDIM * HW;      // 25,165,824 elements
  short* Qhi = (short*)F;                         // bytes [0, 50.3M)
  short* Qlo = Qhi + M25;                         // [50.3, 100.7M)
  short* Kb  = (short*)(F + M25);                 // [100.7, 151M)
  short* Vt  = Kb + M25;                          // [151, 201.3M)
  short* Xhi = (short*)(F + 2 * M25);             // [201.3, 251.7M)
  short* Xlo = Xhi + M25;                         // [251.7, 302M)
  float* tmpf = F + 3 * M25;                      // [302, 377.5M)
  short* WS   = (short*)(F + 3 * M25 + 18874368); // [377.5M, ...)
  short* Wq_hi = WS;             // 576*192
  short* Wq_lo = WS + 110592;
  short* Wp_hi = WS + 221184;    // 192*192
  short* Wp_lo = WS + 258048;
  float* Sums  = (float*)(WS + 294912);           // 32*768 floats
  short* Ebf = (short*)(F + 2 * M25);             // alias X (dead after convs)
  short* Phi = Qhi;                               // alias Q (dead after qk)
  short* Plo = Qlo;

  k_split_w<<<dim3(432), 256, 0, stream>>>(qkv_w, Wq_hi, Wq_lo, 110592);
  k_split_w<<<dim3(144), 256, 0, stream>>>(proj_w, Wp_hi, Wp_lo, 36864);
  k_xsplit<<<dim3(16, 24, 8), 256, 0, stream>>>(x, Xhi, Xlo);
  k_zero<<<dim3(96), 256, 0, stream>>>(Sums, 32 * 768);

  for (int b0 = 0; b0 < 8; b0 += 2) {
    k_cmm<<<dim3(128, 3, 2), 256, 0, stream>>>(
        Xhi + (size_t)b0 * 24 * HW * 8, Xlo + (size_t)b0 * 24 * HW * 8,
        Wq_hi, Wq_lo, qkv_b, tmpf, 576);
    k_dw<<<dim3(576, 2), 256, 0, stream>>>(
        tmpf, dw_w, dw_b, Qhi, Qlo, Kb, Vt, b0);
  }

  k_qk<<<dim3(6, 6, 32), 256, 0, stream>>>(Qhi, Qlo, Kb, temp, Ebf, Sums);
  k_av<<<dim3(8, 6, 32), 256, 0, stream>>>(Ebf, Vt, Sums, Phi, Plo);
  k_cmm<<<dim3(128, 1, 8), 256, 0, stream>>>(
      Phi, Plo, Wp_hi, Wp_lo, proj_b, out, 192);
}